// Round 10
// baseline (214.744 us; speedup 1.0000x reference)
//
#include <hip/hip_runtime.h>
#include <hip/hip_bf16.h>
#include <cstddef>

// ---------------------------------------------------------------------------
// GAT 2-layer fused, MI355X (gfx950).  Round 10 = R9 with ONE fix:
// stage6's two bodies now share a __shared__ UNION (35.9 KB = max, not the
// 70 KB sum that halved occupancy and caused R9's regression).
// 6 kernels: prep -> wcalc/bfrag/sdots1 -> att1||xw1 -> attGEMM1
//            -> sdots2||xw2 -> (att2+e2row) || fat-x2GEMM
// ---------------------------------------------------------------------------

typedef __attribute__((ext_vector_type(8))) short bf16x8;
typedef __attribute__((ext_vector_type(4))) short bf16x4;
typedef __attribute__((ext_vector_type(4))) float f32x4;
typedef unsigned short us;

#define DEVINL static __device__ __forceinline__

DEVINL us f2bf(float f) {
    union { float f; unsigned u; } v; v.f = f;
    return (us)((v.u + 0x7FFFu + ((v.u >> 16) & 1u)) >> 16); // RNE
}
DEVINL float bf2f(us b) {
    union { unsigned u; float f; } v; v.u = ((unsigned)b) << 16; return v.f;
}
DEVINL float wredmax(float v) {
#pragma unroll
    for (int s = 32; s; s >>= 1) v = fmaxf(v, __shfl_xor(v, s));
    return v;
}
DEVINL float wredsum(float v) {
#pragma unroll
    for (int s = 32; s; s >>= 1) v += __shfl_xor(v, s);
    return v;
}

// ---------------- transpose W [h][f][o] f32 -> WT [h][o][f] bf16 ------------
DEVINL void transpose_body(const float* __restrict__ W, us* __restrict__ WT, int bb) {
    __shared__ us tile[64][65];
    const int ft = (bb % 12) * 64, ot = ((bb / 12) % 12) * 64, h = bb / 144;
    const int t = threadIdx.x;
    const float* Wh = W + (size_t)h * 589824;
    us* WTh = WT + (size_t)h * 589824;
#pragma unroll
    for (int i = 0; i < 16; i++) {
        int idx = t + i * 256, r = idx >> 6, c = idx & 63;
        tile[c][r] = f2bf(Wh[(size_t)(ft + r) * 768 + ot + c]);
    }
    __syncthreads();
#pragma unroll
    for (int i = 0; i < 2; i++) {
        int idx = t + i * 256, r = idx >> 3, c0 = (idx & 7) * 8;
        us pk[8];
#pragma unroll
        for (int j = 0; j < 8; j++) pk[j] = tile[r][c0 + j];
        *(bf16x8*)&WTh[(size_t)(ot + r) * 768 + ft + c0] = *(bf16x8*)pk;
    }
}

// ---------------- Mcat via coalesced register-tile GEMM ---------------------
DEVINL void mcat_body(const float* __restrict__ We1, const float* __restrict__ We2,
                      float* __restrict__ Mcat, int h2, int tct) {
    __shared__ float we1L[16][384];
    __shared__ float part[16][128];
    const int t = threadIdx.x;
    for (int i = t; i < 6144; i += 256) {
        int m = i / 384, o = i % 384;
        int h1 = m >> 3, kk = m & 7;
        we1L[m][o] = (kk < 7) ? We1[(h1 * 7 + kk) * 384 + o] : 0.0f;
    }
    __syncthreads();
    const int tc = tct * 128 + (t & 127);
    const int half = t >> 7;
    float acc[16];
#pragma unroll
    for (int m = 0; m < 16; m++) acc[m] = 0.0f;
    const float* w2 = We2 + (size_t)h2 * 147456 + tc;
    for (int o = half * 192; o < half * 192 + 192; o++) {
        float wv = w2[(size_t)o * 384];
#pragma unroll
        for (int m = 0; m < 16; m++) acc[m] += we1L[m][o] * wv;
    }
    if (half == 1)
#pragma unroll
        for (int m = 0; m < 16; m++) part[m][t & 127] = acc[m];
    __syncthreads();
    if (half == 0) {
#pragma unroll
        for (int m = 0; m < 16; m++) {
            float v = 0.25f * (acc[m] + part[m][t]);
            int h1 = m >> 3, kk = m & 7;
            Mcat[((h1 * 2 + h2) * 8 + kk) * 384 + tc] = v;
        }
    }
}

// ---------------- q vectors + u1 --------------------------------------------
DEVINL void pre_qu_body(const float* __restrict__ W1, const float* __restrict__ W2,
                        const float* __restrict__ We1,
                        const float* __restrict__ a1s, const float* __restrict__ a1d,
                        const float* __restrict__ a1e, const float* __restrict__ a2s,
                        const float* __restrict__ a2d,
                        float* __restrict__ q, float* __restrict__ u1, int blk) {
    const int g = blk * 32 + (threadIdx.x >> 3);
    const int lane = threadIdx.x & 7;
    float acc = 0.0f;
    if (g < 6144) {
        int vec = g / 1536, rem = g % 1536, h = rem / 768, f = rem % 768;
        const float* W = (vec < 2) ? W1 : W2;
        const float* a = (vec == 0) ? a1s : (vec == 1) ? a1d : (vec == 2) ? a2s : a2d;
        const float* wr = W + (size_t)(h * 768 + f) * 768;
        const float* ar = a + h * 768;
        for (int o = lane; o < 768; o += 8) acc += wr[o] * ar[o];
        for (int s = 4; s; s >>= 1) acc += __shfl_down(acc, s, 8);
        if (lane == 0) q[g] = acc;
    } else if (g < 6160) {
        int g2 = g - 6144, h = g2 >> 3, k = g2 & 7;
        if (k < 7) {
            const float* wr = We1 + (h * 7 + k) * 384;
            const float* ar = a1e + h * 384;
            for (int o = lane; o < 384; o += 8) acc += wr[o] * ar[o];
        }
        for (int s = 4; s; s >>= 1) acc += __shfl_down(acc, s, 8);
        if (lane == 0) u1[g2] = acc;
    }
}

// ---------------- f32 -> bf16 convert (x8) ----------------------------------
DEVINL void cvt_body(const float* __restrict__ in, us* __restrict__ out, int blk) {
    int i = (blk * 256 + threadIdx.x) * 8;
    float4 v0 = *(const float4*)&in[i];
    float4 v1 = *(const float4*)&in[i + 4];
    us pk[8] = {f2bf(v0.x), f2bf(v0.y), f2bf(v0.z), f2bf(v0.w),
                f2bf(v1.x), f2bf(v1.y), f2bf(v1.z), f2bf(v1.w)};
    *(bf16x8*)&out[i] = *(bf16x8*)pk;
}

// ---------------- w[h1][h2][8] ----------------------------------------------
DEVINL void wcalc_body(const float* __restrict__ Mcat, const float* __restrict__ a2e,
                       float* __restrict__ w) {
    const int t = threadIdx.x, g = t >> 3, lane = t & 7;
    int hh = g >> 3, k = g & 7, h2 = hh & 1;
    float acc = 0.0f;
    if (k < 7)
        for (int o = lane; o < 384; o += 8) acc += Mcat[(hh * 8 + k) * 384 + o] * a2e[h2 * 384 + o];
    for (int s = 4; s; s >>= 1) acc += __shfl_down(acc, s, 8);
    if (lane == 0) w[g] = 2.0f * acc; // * H
}

// ---------------- Bfrag[ct][64][8] from Mcat --------------------------------
DEVINL void bfrag_body(const float* __restrict__ Mcat, us* __restrict__ Bfrag, int ct) {
    const int l = threadIdx.x;
    if (l < 64) {
        us pk[8];
#pragma unroll
        for (int j = 0; j < 8; j++)
            pk[j] = f2bf(Mcat[((l >> 4) * 8 + j) * 384 + ct * 16 + (l & 15)]);
        *(bf16x8*)&Bfrag[(ct * 64 + l) * 8] = *(bf16x8*)pk;
    }
}

// ---------------- s_src/s_dst dots (f32), shfl-reduced ----------------------
DEVINL void sdots_body(const float* __restrict__ x, const float* __restrict__ qs,
                       const float* __restrict__ qd, float* __restrict__ out_s,
                       float* __restrict__ out_d, int n, int b) {
    const int t = threadIdx.x, wv = t >> 6;
    const float* xr = x + (size_t)(b * 256 + n) * 768;
    float a0 = 0, a1 = 0, a2 = 0, a3 = 0;
#pragma unroll
    for (int i = 0; i < 3; i++) {
        int k = i * 256 + t;
        float xv = xr[k];
        a0 += xv * qs[k];
        a1 += xv * qs[768 + k];
        a2 += xv * qd[k];
        a3 += xv * qd[768 + k];
    }
    a0 = wredsum(a0); a1 = wredsum(a1); a2 = wredsum(a2); a3 = wredsum(a3);
    __shared__ float part[4][4];
    if ((t & 63) == 0) { part[wv][0] = a0; part[wv][1] = a1; part[wv][2] = a2; part[wv][3] = a3; }
    __syncthreads();
    if (t == 0) {
        float r0 = 0, r1 = 0, r2 = 0, r3 = 0;
#pragma unroll
        for (int i = 0; i < 4; i++) { r0 += part[i][0]; r1 += part[i][1]; r2 += part[i][2]; r3 += part[i][3]; }
        out_s[(b * 2 + 0) * 256 + n] = r0;
        out_s[(b * 2 + 1) * 256 + n] = r1;
        out_d[(b * 2 + 0) * 256 + n] = r2;
        out_d[(b * 2 + 1) * 256 + n] = r3;
    }
}

// ---------------- layer-1 attention (both heads per block) ------------------
DEVINL void att1_body(const float* __restrict__ e, const int* __restrict__ adj,
                      const float* __restrict__ s_s, const float* __restrict__ s_d,
                      const float* __restrict__ u1, us* __restrict__ attb,
                      int n, int bb) {
    __shared__ float eL[1792];
    __shared__ float smax[2][4], ssum[2][4];
    const int t = threadIdx.x, wv = t >> 6;
    const float* erow = e + (size_t)(bb * 256 + n) * 1792;
#pragma unroll
    for (int i = 0; i < 7; i++) eL[t + i * 256] = erow[t + i * 256];
    __syncthreads();
    float ss0 = s_s[(bb * 2 + 0) * 256 + n], ss1 = s_s[(bb * 2 + 1) * 256 + n];
    float sd0 = s_d[(bb * 2 + 0) * 256 + t], sd1 = s_d[(bb * 2 + 1) * 256 + t];
    float se0 = 0, se1 = 0;
#pragma unroll
    for (int k = 0; k < 7; k++) {
        float ev = eL[t * 7 + k];
        se0 += ev * u1[k];
        se1 += ev * u1[8 + k];
    }
    float sc0 = ss0 + sd0 + se0, sc1 = ss1 + sd1 + se1;
    sc0 = sc0 > 0.0f ? sc0 : 0.2f * sc0;
    sc1 = sc1 > 0.0f ? sc1 : 0.2f * sc1;
    bool ok = adj[(size_t)(bb * 256 + n) * 256 + t] > 0;
    sc0 = ok ? sc0 : -9e15f;
    sc1 = ok ? sc1 : -9e15f;
    float w0 = wredmax(sc0), w1 = wredmax(sc1);
    if ((t & 63) == 0) { smax[0][wv] = w0; smax[1][wv] = w1; }
    __syncthreads();
    float mx0 = fmaxf(fmaxf(smax[0][0], smax[0][1]), fmaxf(smax[0][2], smax[0][3]));
    float mx1 = fmaxf(fmaxf(smax[1][0], smax[1][1]), fmaxf(smax[1][2], smax[1][3]));
    float ex0 = __expf(sc0 - mx0), ex1 = __expf(sc1 - mx1);
    float su0 = wredsum(ex0), su1 = wredsum(ex1);
    if ((t & 63) == 0) { ssum[0][wv] = su0; ssum[1][wv] = su1; }
    __syncthreads();
    float i0 = 1.0f / (ssum[0][0] + ssum[0][1] + ssum[0][2] + ssum[0][3]);
    float i1 = 1.0f / (ssum[1][0] + ssum[1][1] + ssum[1][2] + ssum[1][3]);
    attb[((size_t)(bb * 2 + 0) * 256 + n) * 256 + t] = f2bf(ex0 * i0);
    attb[((size_t)(bb * 2 + 1) * 256 + n) * 256 + t] = f2bf(ex1 * i1);
}

// ---------------- Wh^T = (x @ W)^T via bf16 MFMA (64x64 tiles) --------------
DEVINL void gemm_xw_body(const us* __restrict__ A, const us* __restrict__ BT,
                         us* __restrict__ WhT, int mt, int ot, int h) {
    const int t = threadIdx.x, wv = t >> 6, l = t & 63;
    const int wm = wv >> 1, wn = wv & 1, lr = l & 15, lk = l >> 4;
    __shared__ us As[64][40];
    __shared__ us Bs[64][40];
    const int arow = t >> 2, acol = (t & 3) * 8;
    const us* Bh = BT + (size_t)h * 589824;
    f32x4 acc[2][2];
#pragma unroll
    for (int i = 0; i < 2; i++)
#pragma unroll
        for (int j = 0; j < 2; j++) acc[i][j] = (f32x4){0, 0, 0, 0};
    for (int k0 = 0; k0 < 768; k0 += 32) {
        __syncthreads();
        *(bf16x8*)&As[arow][acol] = *(const bf16x8*)&A[(size_t)(mt * 64 + arow) * 768 + k0 + acol];
        *(bf16x8*)&Bs[arow][acol] = *(const bf16x8*)&Bh[(size_t)(ot * 64 + arow) * 768 + k0 + acol];
        __syncthreads();
        bf16x8 af[2], bfv[2];
#pragma unroll
        for (int i = 0; i < 2; i++) af[i] = *(const bf16x8*)&As[wm * 32 + i * 16 + lr][lk * 8];
#pragma unroll
        for (int j = 0; j < 2; j++) bfv[j] = *(const bf16x8*)&Bs[wn * 32 + j * 16 + lr][lk * 8];
#pragma unroll
        for (int i = 0; i < 2; i++)
#pragma unroll
            for (int j = 0; j < 2; j++)
                acc[i][j] = __builtin_amdgcn_mfma_f32_16x16x32_bf16(af[i], bfv[j], acc[i][j], 0, 0, 0);
    }
#pragma unroll
    for (int i = 0; i < 2; i++)
#pragma unroll
        for (int j = 0; j < 2; j++) {
            int n0 = mt * 64 + wm * 32 + i * 16 + lk * 4;
            int og = ot * 64 + wn * 32 + j * 16 + lr;
            int b = n0 >> 8, n = n0 & 255;
            us pk[4];
#pragma unroll
            for (int r = 0; r < 4; r++) pk[r] = f2bf(acc[i][j][r]);
            *(bf16x4*)&WhT[((size_t)(b * 2 + h) * 768 + og) * 256 + n] = *(bf16x4*)pk;
        }
}

// ------- x' = 0.5*(elu(att@Wh)_h0+elu_h1)+resid (32x64 tiles) ---------------
DEVINL void gemm_att_body(const us* __restrict__ attb, const us* __restrict__ WhT,
                          const float* __restrict__ resid, float* __restrict__ xout,
                          us* __restrict__ xbout, int mt, int ot, int b) {
    const int t = threadIdx.x, wv = t >> 6, l = t & 63;
    const int wm = wv >> 1, wn = wv & 1, lr = l & 15, lk = l >> 4;
    __shared__ us As2[32][40];
    __shared__ us Bs2[64][40];
    float res[2][4] = {};
    for (int h = 0; h < 2; h++) {
        const us* Ah = attb + (size_t)(b * 2 + h) * 65536;
        const us* Bh = WhT + (size_t)(b * 2 + h) * 196608;
        f32x4 acc[2];
        acc[0] = (f32x4){0, 0, 0, 0};
        acc[1] = (f32x4){0, 0, 0, 0};
        for (int k0 = 0; k0 < 256; k0 += 32) {
            __syncthreads();
            if (t < 128) {
                int ar = t >> 2, ac = (t & 3) * 8;
                *(bf16x8*)&As2[ar][ac] = *(const bf16x8*)&Ah[(size_t)(mt * 32 + ar) * 256 + k0 + ac];
            }
            {
                int br = t >> 2, bc = (t & 3) * 8;
                *(bf16x8*)&Bs2[br][bc] = *(const bf16x8*)&Bh[(size_t)(ot * 64 + br) * 256 + k0 + bc];
            }
            __syncthreads();
            bf16x8 af = *(const bf16x8*)&As2[wm * 16 + lr][lk * 8];
#pragma unroll
            for (int j = 0; j < 2; j++) {
                bf16x8 bv = *(const bf16x8*)&Bs2[wn * 32 + j * 16 + lr][lk * 8];
                acc[j] = __builtin_amdgcn_mfma_f32_16x16x32_bf16(af, bv, acc[j], 0, 0, 0);
            }
        }
#pragma unroll
        for (int j = 0; j < 2; j++)
#pragma unroll
            for (int r = 0; r < 4; r++) {
                float v = acc[j][r];
                res[j][r] += (v > 0.0f ? v : (expf(v) - 1.0f)); // elu
            }
        __syncthreads();
    }
#pragma unroll
    for (int j = 0; j < 2; j++) {
        int n0 = mt * 32 + wm * 16 + lk * 4;
        int og = ot * 64 + wn * 32 + j * 16 + lr;
#pragma unroll
        for (int r = 0; r < 4; r++) {
            size_t idx = (size_t)(b * 256 + n0 + r) * 768 + og;
            float v = 0.5f * res[j][r] + resid[idx];
            if (xout) xout[idx] = v;
            if (xbout) xbout[idx] = f2bf(v);
        }
    }
}

// ---------------- stage-6 shared-memory union (max, not sum) ----------------
union Smem6 {
    struct {
        us    blB[1536 * 8];       // 24576 B
        float eL[1792];            // 7168 B
        float aL1[2][256];         // 2048 B
        float aL2[2][256];         // 2048 B
        float smax[2][4];          // 32 B
        float ssum[2][4];          // 32 B
    } a;                           // 35904 B total
    struct {
        us aA[2][32][264];         // 33792 B
    } b;
};

// ---------------- fused att2 + e2 row stream --------------------------------
DEVINL void att2e2_body(const float* __restrict__ e, const int* __restrict__ adj,
                        const float* __restrict__ s_s, const float* __restrict__ s_d,
                        const float* __restrict__ w, const us* __restrict__ att1b,
                        const us* __restrict__ Bfrag, float* __restrict__ e2out,
                        Smem6& sm, int bb, int n) {
    const int t = threadIdx.x, wv4 = t >> 6;
    for (int i = t; i < 1536; i += 256)
        *(bf16x8*)&sm.a.blB[i * 8] = *(const bf16x8*)&Bfrag[(size_t)i * 8];
    const float* erow = e + (size_t)(bb * 256 + n) * 1792;
#pragma unroll
    for (int i = 0; i < 7; i++) sm.a.eL[t + i * 256] = erow[t + i * 256];
    const size_t a1base = (size_t)bb * 131072 + n * 256;
    float a10 = bf2f(att1b[a1base + t]);
    float a11 = bf2f(att1b[a1base + 65536 + t]);
    sm.a.aL1[0][t] = a10;
    sm.a.aL1[1][t] = a11;
    __syncthreads();
    float ss0 = s_s[(bb * 2 + 0) * 256 + n], ss1 = s_s[(bb * 2 + 1) * 256 + n];
    float sd0 = s_d[(bb * 2 + 0) * 256 + t], sd1 = s_d[(bb * 2 + 1) * 256 + t];
    float ew00 = 0, ew01 = 0, ew10 = 0, ew11 = 0;
#pragma unroll
    for (int k = 0; k < 7; k++) {
        float ev = sm.a.eL[t * 7 + k];
        ew00 += ev * w[k];
        ew01 += ev * w[8 + k];
        ew10 += ev * w[16 + k];
        ew11 += ev * w[24 + k];
    }
    float sc0 = ss0 + sd0 + a10 * ew00 + a11 * ew10;
    float sc1 = ss1 + sd1 + a10 * ew01 + a11 * ew11;
    sc0 = sc0 > 0.0f ? sc0 : 0.2f * sc0;
    sc1 = sc1 > 0.0f ? sc1 : 0.2f * sc1;
    bool ok = adj[(size_t)(bb * 256 + n) * 256 + t] > 0;
    sc0 = ok ? sc0 : -9e15f;
    sc1 = ok ? sc1 : -9e15f;
    float w0 = wredmax(sc0), w1 = wredmax(sc1);
    if ((t & 63) == 0) { sm.a.smax[0][wv4] = w0; sm.a.smax[1][wv4] = w1; }
    __syncthreads();
    float mx0 = fmaxf(fmaxf(sm.a.smax[0][0], sm.a.smax[0][1]), fmaxf(sm.a.smax[0][2], sm.a.smax[0][3]));
    float mx1 = fmaxf(fmaxf(sm.a.smax[1][0], sm.a.smax[1][1]), fmaxf(sm.a.smax[1][2], sm.a.smax[1][3]));
    float ex0 = __expf(sc0 - mx0), ex1 = __expf(sc1 - mx1);
    float su0 = wredsum(ex0), su1 = wredsum(ex1);
    if ((t & 63) == 0) { sm.a.ssum[0][wv4] = su0; sm.a.ssum[1][wv4] = su1; }
    __syncthreads();
    float i0 = 1.0f / (sm.a.ssum[0][0] + sm.a.ssum[0][1] + sm.a.ssum[0][2] + sm.a.ssum[0][3]);
    float i1 = 1.0f / (sm.a.ssum[1][0] + sm.a.ssum[1][1] + sm.a.ssum[1][2] + sm.a.ssum[1][3]);
    sm.a.aL2[0][t] = ex0 * i0;
    sm.a.aL2[1][t] = ex1 * i1;
    __syncthreads();
    // e2 stream
    const int wv = t >> 6, l = t & 63, le = l & 15, lq = l >> 4;
    const int h1 = lq >> 1, h2 = lq & 1;
    bf16x8 av[4];
#pragma unroll
    for (int g = 0; g < 4; g++) {
        int m = g * 64 + wv * 16 + le;
        float c = sm.a.aL1[h1][m] * sm.a.aL2[h2][m];
        us pk[8];
#pragma unroll
        for (int j = 0; j < 7; j++) pk[j] = f2bf(c * sm.a.eL[m * 7 + j]);
        pk[7] = 0;
        av[g] = *(bf16x8*)pk;
    }
    const f32x4 zero = {0, 0, 0, 0};
    const size_t rowbase = (size_t)bb * 65536 + n * 256;
#pragma unroll
    for (int cg = 0; cg < 3; cg++) {
        bf16x8 bfr[8];
#pragma unroll
        for (int i = 0; i < 8; i++) bfr[i] = *(const bf16x8*)&sm.a.blB[(cg * 512 + i * 64 + l) * 8];
        for (int g = 0; g < 4; g++) {
            size_t eidx = rowbase + g * 64 + wv * 16 + le;
#pragma unroll
            for (int i = 0; i < 8; i++) {
                f32x4 acc = __builtin_amdgcn_mfma_f32_16x16x32_bf16(bfr[i], av[g], zero, 0, 0, 0);
                *(f32x4*)&e2out[eidx * 384 + cg * 128 + i * 16 + lq * 4] = acc;
            }
        }
    }
}

// ---------------- fat x2 GEMM: recompute att2 for 32 rows, GEMM 32x768 ------
DEVINL void gemm_att2_fat(const float* __restrict__ e, const int* __restrict__ adj,
                          const float* __restrict__ s2s, const float* __restrict__ s2d,
                          const float* __restrict__ wbuf, const us* __restrict__ att1b,
                          const us* __restrict__ WhT2, const float* __restrict__ resid,
                          float* __restrict__ x2out, Smem6& sm, int mt, int b) {
    const int t = threadIdx.x, wv = t >> 6, l = t & 63;
    // ---- phase A: wave wv computes att2 for rows r = wv*8 .. wv*8+7
    for (int rr = 0; rr < 8; rr++) {
        const int r = wv * 8 + rr, n = mt * 32 + r, m0 = l * 4;
        const float* ep = e + ((size_t)(b * 256 + n) * 256 + m0) * 7;
        float ev[4][7];
#pragma unroll
        for (int mm = 0; mm < 4; mm++)
#pragma unroll
            for (int k = 0; k < 7; k++) ev[mm][k] = ep[mm * 7 + k];
        const int* adjp = adj + (size_t)(b * 256 + n) * 256 + m0;
        float ss0 = s2s[(b * 2 + 0) * 256 + n], ss1 = s2s[(b * 2 + 1) * 256 + n];
        float sc0[4], sc1[4];
#pragma unroll
        for (int mm = 0; mm < 4; mm++) {
            int m = m0 + mm;
            float sd0 = s2d[(b * 2 + 0) * 256 + m];
            float sd1 = s2d[(b * 2 + 1) * 256 + m];
            float a10 = bf2f(att1b[((size_t)(b * 2 + 0) * 256 + n) * 256 + m]);
            float a11 = bf2f(att1b[((size_t)(b * 2 + 1) * 256 + n) * 256 + m]);
            float ew00 = 0, ew01 = 0, ew10 = 0, ew11 = 0;
#pragma unroll
            for (int k = 0; k < 7; k++) {
                float evk = ev[mm][k];
                ew00 += evk * wbuf[k];
                ew01 += evk * wbuf[8 + k];
                ew10 += evk * wbuf[16 + k];
                ew11 += evk * wbuf[24 + k];
            }
            float s0 = ss0 + sd0 + a10 * ew00 + a11 * ew10;
            float s1 = ss1 + sd1 + a10 * ew01 + a11 * ew11;
            s0 = s0 > 0.0f ? s0 : 0.2f * s0;
            s1 = s1 > 0.0f ? s1 : 0.2f * s1;
            bool ok = adjp[mm] > 0;
            sc0[mm] = ok ? s0 : -9e15f;
            sc1[mm] = ok ? s1 : -9e15f;
        }
        float mx0 = fmaxf(fmaxf(sc0[0], sc0[1]), fmaxf(sc0[2], sc0[3]));
        float mx1 = fmaxf(fmaxf(sc1[0], sc1[1]), fmaxf(sc1[2], sc1[3]));
        mx0 = wredmax(mx0); mx1 = wredmax(mx1);
        float ex0[4], ex1[4], su0 = 0, su1 = 0;
#pragma unroll
        for (int mm = 0; mm < 4; mm++) {
            ex0[mm] = __expf(sc0[mm] - mx0); su0 += ex0[mm];
            ex1[mm] = __expf(sc1[mm] - mx1); su1 += ex1[mm];
        }
        su0 = wredsum(su0); su1 = wredsum(su1);
        float i0 = 1.0f / su0, i1 = 1.0f / su1;
        us p0[4], p1[4];
#pragma unroll
        for (int mm = 0; mm < 4; mm++) { p0[mm] = f2bf(ex0[mm] * i0); p1[mm] = f2bf(ex1[mm] * i1); }
        *(bf16x4*)&sm.b.aA[0][r][m0] = *(bf16x4*)p0;
        *(bf16x4*)&sm.b.aA[1][r][m0] = *(bf16x4*)p1;
    }
    __syncthreads();
    // ---- phase B: GEMM 32x768, A from LDS, B direct from global (L2/L3-hot)
    const int wm = wv >> 1, wn = wv & 1, lr = l & 15, lk = l >> 4;
    for (int ot = 0; ot < 12; ot++) {
        float res[2][4] = {};
        for (int h = 0; h < 2; h++) {
            const us* Bh = WhT2 + (size_t)(b * 2 + h) * 196608;
            f32x4 acc[2];
            acc[0] = (f32x4){0, 0, 0, 0};
            acc[1] = (f32x4){0, 0, 0, 0};
            for (int k0 = 0; k0 < 256; k0 += 32) {
                bf16x8 af = *(const bf16x8*)&sm.b.aA[h][wm * 16 + lr][k0 + lk * 8];
#pragma unroll
                for (int j = 0; j < 2; j++) {
                    bf16x8 bv = *(const bf16x8*)&Bh[(size_t)(ot * 64 + wn * 32 + j * 16 + lr) * 256 + k0 + lk * 8];
                    acc[j] = __builtin_amdgcn_mfma_f32_16x16x32_bf16(af, bv, acc[j], 0, 0, 0);
                }
            }
#pragma unroll
            for (int j = 0; j < 2; j++)
#pragma unroll
                for (int r = 0; r < 4; r++) {
                    float v = acc[j][r];
                    res[j][r] += (v > 0.0f ? v : (expf(v) - 1.0f)); // elu
                }
        }
#pragma unroll
        for (int j = 0; j < 2; j++) {
            int n0 = mt * 32 + wm * 16 + lk * 4;
            int og = ot * 64 + wn * 32 + j * 16 + lr;
#pragma unroll
            for (int r = 0; r < 4; r++) {
                size_t idx = (size_t)(b * 256 + n0 + r) * 768 + og;
                x2out[idx] = 0.5f * res[j][r] + resid[idx];
            }
        }
    }
}

// ========================= stage kernels ====================================
__global__ __launch_bounds__(256) void stage1(
    const float* W1, const float* W2, const float* We1, const float* We2,
    const float* a1s, const float* a1d, const float* a1e,
    const float* a2s, const float* a2d, const float* x,
    us* W1T, us* W2T, us* xb, float* q, float* u1, float* Mcat) {
    int b = blockIdx.x;
    if (b < 6)          mcat_body(We1, We2, Mcat, b & 1, b >> 1);
    else if (b < 199)   pre_qu_body(W1, W2, We1, a1s, a1d, a1e, a2s, a2d, q, u1, b - 6);
    else if (b < 487)   transpose_body(W1, W1T, b - 199);
    else if (b < 775)   transpose_body(W2, W2T, b - 487);
    else                cvt_body(x, xb, b - 775);
}

__global__ __launch_bounds__(256) void stage2(
    const float* Mcat, const float* a2e, float* wbuf, us* Bfrag,
    const float* x, const float* qs, const float* qd, float* s1s, float* s1d) {
    int b = blockIdx.x;
    if (b < 1)        wcalc_body(Mcat, a2e, wbuf);
    else if (b < 25)  bfrag_body(Mcat, Bfrag, b - 1);
    else { int i = b - 25; sdots_body(x, qs, qd, s1s, s1d, i & 255, i >> 8); }
}

__global__ __launch_bounds__(256) void stage3(
    const float* e, const int* adj, const float* s1s, const float* s1d,
    const float* u1, us* att1b, const us* xb, const us* W1T, us* WhT1) {
    int b = blockIdx.x;
    if (b < 512) att1_body(e, adj, s1s, s1d, u1, att1b, b & 255, b >> 8);
    else { int g = b - 512; gemm_xw_body(xb, W1T, WhT1, g & 7, (g >> 3) % 12, g / 96); }
}

__global__ __launch_bounds__(256) void stage4(
    const us* att1b, const us* WhT1, const float* x, float* x1, us* xb1) {
    int b = blockIdx.x;
    gemm_att_body(att1b, WhT1, x, x1, xb1, b & 7, (b >> 3) % 12, b / 96);
}

__global__ __launch_bounds__(256) void stage5(
    const float* x1, const float* qs, const float* qd, float* s2s, float* s2d,
    const us* xb1, const us* W2T, us* WhT2) {
    int b = blockIdx.x;
    if (b < 512) sdots_body(x1, qs, qd, s2s, s2d, b & 255, b >> 8);
    else { int g = b - 512; gemm_xw_body(xb1, W2T, WhT2, g & 7, (g >> 3) % 12, g / 96); }
}

__global__ __launch_bounds__(256) void stage6(
    const float* e, const int* adj, const float* s2s, const float* s2d,
    const float* wbuf, const us* att1b, const us* Bfrag, float* e2out,
    const us* WhT2, const float* x, float* x2out) {
    __shared__ Smem6 sm;   // UNION: 35.9 KB (max of both branches, not sum)
    int b = blockIdx.x;
    if (b < 16) gemm_att2_fat(e, adj, s2s, s2d, wbuf, att1b, WhT2, x, x2out,
                              sm, b >> 1, b & 1);
    else { int r = b - 16; att2e2_body(e, adj, s2s, s2d, wbuf, att1b, Bfrag, e2out,
                                       sm, r >> 8, r & 255); }
}

// ---------------------------------------------------------------------------
extern "C" void kernel_launch(void* const* d_in, const int* in_sizes, int n_in,
                              void* d_out, int out_size, void* d_ws, size_t ws_size,
                              hipStream_t stream) {
    const float* x   = (const float*)d_in[0];
    const int*   adj = (const int*)d_in[1];
    const float* e   = (const float*)d_in[2];
    const float* W1  = (const float*)d_in[3];
    const float* We1 = (const float*)d_in[4];
    const float* a1s = (const float*)d_in[5];
    const float* a1d = (const float*)d_in[6];
    const float* a1e = (const float*)d_in[7];
    const float* W2  = (const float*)d_in[8];
    const float* We2 = (const float*)d_in[9];
    const float* a2s = (const float*)d_in[10];
    const float* a2d = (const float*)d_in[11];
    const float* a2e = (const float*)d_in[12];

    float* out   = (float*)d_out;
    float* x2out = out;                  // [2][256][768]
    float* e2out = out + 393216;         // [2][256][256][384]

    char* ws = (char*)d_ws;
    float* q     = (float*)(ws + 0);         // [4][2][768]
    float* u1    = (float*)(ws + 24576);     // [2][8]
    float* wbuf  = (float*)(ws + 24640);     // [2][2][8]
    float* Mcat  = (float*)(ws + 24832);     // [32][384]
    us*    Bfrag = (us*)(ws + 73984);        // [24][64][8]
    float* s1s   = (float*)(ws + 98560);
    float* s1d   = (float*)(ws + 102656);
    float* s2s   = (float*)(ws + 106752);
    float* s2d   = (float*)(ws + 110848);
    us*    att1b = (us*)(ws + 114944);       // [2][2][256][256] bf16
    us*    W1T   = (us*)(ws + 1163520);      // [2][768][768] bf16
    us*    W2T   = (us*)(ws + 3522816);
    us*    xb    = (us*)(ws + 5882112);      // [512][768] bf16
    us*    xb1   = (us*)(ws + 6668544);
    us*    WhT1  = (us*)(ws + 7454976);      // [2][2][768][256] bf16
    us*    WhT2  = (us*)(ws + 9027840);
    float* x1    = (float*)(ws + 10600704);  // [512][768] f32

    stage1<<<967, 256, 0, stream>>>(W1, W2, We1, We2, a1s, a1d, a1e, a2s, a2d,
                                    x, W1T, W2T, xb, q, u1, Mcat);
    stage2<<<537, 256, 0, stream>>>(Mcat, a2e, wbuf, Bfrag, x, q + 0, q + 1536, s1s, s1d);
    stage3<<<704, 256, 0, stream>>>(e, adj, s1s, s1d, u1, att1b, xb, W1T, WhT1);
    stage4<<<192, 256, 0, stream>>>(att1b, WhT1, x, x1, xb1);
    stage5<<<704, 256, 0, stream>>>(x1, q + 3072, q + 4608, s2s, s2d, xb1, W2T, WhT2);
    stage6<<<528, 256, 0, stream>>>(e, adj, s2s, s2d, wbuf, att1b, Bfrag, e2out,
                                    WhT2, x, x2out);
}

// Round 11
// 112.880 us; speedup vs baseline: 1.9024x; 1.9024x over previous
//
#include <hip/hip_runtime.h>
#include <hip/hip_bf16.h>
#include <cstddef>

// ---------------------------------------------------------------------------
// GAT 2-layer fused, MI355X (gfx950).  Round 11 = R10 with ONE fix:
// fat x2 branch now 192 blocks (mt x ot x b) with LDS-staged B (R4's proven
// staging), killing R10's 136us latency-bound 16-block tail.
// 6 kernels: prep -> wcalc/bfrag/sdots1 -> att1||xw1 -> attGEMM1
//            -> sdots2||xw2 -> (att2+e2row) || fat-x2GEMM(192)
// ---------------------------------------------------------------------------

typedef __attribute__((ext_vector_type(8))) short bf16x8;
typedef __attribute__((ext_vector_type(4))) short bf16x4;
typedef __attribute__((ext_vector_type(4))) float f32x4;
typedef unsigned short us;

#define DEVINL static __device__ __forceinline__

DEVINL us f2bf(float f) {
    union { float f; unsigned u; } v; v.f = f;
    return (us)((v.u + 0x7FFFu + ((v.u >> 16) & 1u)) >> 16); // RNE
}
DEVINL float bf2f(us b) {
    union { unsigned u; float f; } v; v.u = ((unsigned)b) << 16; return v.f;
}
DEVINL float wredmax(float v) {
#pragma unroll
    for (int s = 32; s; s >>= 1) v = fmaxf(v, __shfl_xor(v, s));
    return v;
}
DEVINL float wredsum(float v) {
#pragma unroll
    for (int s = 32; s; s >>= 1) v += __shfl_xor(v, s);
    return v;
}

// ---------------- transpose W [h][f][o] f32 -> WT [h][o][f] bf16 ------------
DEVINL void transpose_body(const float* __restrict__ W, us* __restrict__ WT, int bb) {
    __shared__ us tile[64][65];
    const int ft = (bb % 12) * 64, ot = ((bb / 12) % 12) * 64, h = bb / 144;
    const int t = threadIdx.x;
    const float* Wh = W + (size_t)h * 589824;
    us* WTh = WT + (size_t)h * 589824;
#pragma unroll
    for (int i = 0; i < 16; i++) {
        int idx = t + i * 256, r = idx >> 6, c = idx & 63;
        tile[c][r] = f2bf(Wh[(size_t)(ft + r) * 768 + ot + c]);
    }
    __syncthreads();
#pragma unroll
    for (int i = 0; i < 2; i++) {
        int idx = t + i * 256, r = idx >> 3, c0 = (idx & 7) * 8;
        us pk[8];
#pragma unroll
        for (int j = 0; j < 8; j++) pk[j] = tile[r][c0 + j];
        *(bf16x8*)&WTh[(size_t)(ot + r) * 768 + ft + c0] = *(bf16x8*)pk;
    }
}

// ---------------- Mcat via coalesced register-tile GEMM ---------------------
DEVINL void mcat_body(const float* __restrict__ We1, const float* __restrict__ We2,
                      float* __restrict__ Mcat, int h2, int tct) {
    __shared__ float we1L[16][384];
    __shared__ float part[16][128];
    const int t = threadIdx.x;
    for (int i = t; i < 6144; i += 256) {
        int m = i / 384, o = i % 384;
        int h1 = m >> 3, kk = m & 7;
        we1L[m][o] = (kk < 7) ? We1[(h1 * 7 + kk) * 384 + o] : 0.0f;
    }
    __syncthreads();
    const int tc = tct * 128 + (t & 127);
    const int half = t >> 7;
    float acc[16];
#pragma unroll
    for (int m = 0; m < 16; m++) acc[m] = 0.0f;
    const float* w2 = We2 + (size_t)h2 * 147456 + tc;
    for (int o = half * 192; o < half * 192 + 192; o++) {
        float wv = w2[(size_t)o * 384];
#pragma unroll
        for (int m = 0; m < 16; m++) acc[m] += we1L[m][o] * wv;
    }
    if (half == 1)
#pragma unroll
        for (int m = 0; m < 16; m++) part[m][t & 127] = acc[m];
    __syncthreads();
    if (half == 0) {
#pragma unroll
        for (int m = 0; m < 16; m++) {
            float v = 0.25f * (acc[m] + part[m][t]);
            int h1 = m >> 3, kk = m & 7;
            Mcat[((h1 * 2 + h2) * 8 + kk) * 384 + tc] = v;
        }
    }
}

// ---------------- q vectors + u1 --------------------------------------------
DEVINL void pre_qu_body(const float* __restrict__ W1, const float* __restrict__ W2,
                        const float* __restrict__ We1,
                        const float* __restrict__ a1s, const float* __restrict__ a1d,
                        const float* __restrict__ a1e, const float* __restrict__ a2s,
                        const float* __restrict__ a2d,
                        float* __restrict__ q, float* __restrict__ u1, int blk) {
    const int g = blk * 32 + (threadIdx.x >> 3);
    const int lane = threadIdx.x & 7;
    float acc = 0.0f;
    if (g < 6144) {
        int vec = g / 1536, rem = g % 1536, h = rem / 768, f = rem % 768;
        const float* W = (vec < 2) ? W1 : W2;
        const float* a = (vec == 0) ? a1s : (vec == 1) ? a1d : (vec == 2) ? a2s : a2d;
        const float* wr = W + (size_t)(h * 768 + f) * 768;
        const float* ar = a + h * 768;
        for (int o = lane; o < 768; o += 8) acc += wr[o] * ar[o];
        for (int s = 4; s; s >>= 1) acc += __shfl_down(acc, s, 8);
        if (lane == 0) q[g] = acc;
    } else if (g < 6160) {
        int g2 = g - 6144, h = g2 >> 3, k = g2 & 7;
        if (k < 7) {
            const float* wr = We1 + (h * 7 + k) * 384;
            const float* ar = a1e + h * 384;
            for (int o = lane; o < 384; o += 8) acc += wr[o] * ar[o];
        }
        for (int s = 4; s; s >>= 1) acc += __shfl_down(acc, s, 8);
        if (lane == 0) u1[g2] = acc;
    }
}

// ---------------- f32 -> bf16 convert (x8) ----------------------------------
DEVINL void cvt_body(const float* __restrict__ in, us* __restrict__ out, int blk) {
    int i = (blk * 256 + threadIdx.x) * 8;
    float4 v0 = *(const float4*)&in[i];
    float4 v1 = *(const float4*)&in[i + 4];
    us pk[8] = {f2bf(v0.x), f2bf(v0.y), f2bf(v0.z), f2bf(v0.w),
                f2bf(v1.x), f2bf(v1.y), f2bf(v1.z), f2bf(v1.w)};
    *(bf16x8*)&out[i] = *(bf16x8*)pk;
}

// ---------------- w[h1][h2][8] ----------------------------------------------
DEVINL void wcalc_body(const float* __restrict__ Mcat, const float* __restrict__ a2e,
                       float* __restrict__ w) {
    const int t = threadIdx.x, g = t >> 3, lane = t & 7;
    int hh = g >> 3, k = g & 7, h2 = hh & 1;
    float acc = 0.0f;
    if (k < 7)
        for (int o = lane; o < 384; o += 8) acc += Mcat[(hh * 8 + k) * 384 + o] * a2e[h2 * 384 + o];
    for (int s = 4; s; s >>= 1) acc += __shfl_down(acc, s, 8);
    if (lane == 0) w[g] = 2.0f * acc; // * H
}

// ---------------- Bfrag[ct][64][8] from Mcat --------------------------------
DEVINL void bfrag_body(const float* __restrict__ Mcat, us* __restrict__ Bfrag, int ct) {
    const int l = threadIdx.x;
    if (l < 64) {
        us pk[8];
#pragma unroll
        for (int j = 0; j < 8; j++)
            pk[j] = f2bf(Mcat[((l >> 4) * 8 + j) * 384 + ct * 16 + (l & 15)]);
        *(bf16x8*)&Bfrag[(ct * 64 + l) * 8] = *(bf16x8*)pk;
    }
}

// ---------------- s_src/s_dst dots (f32), shfl-reduced ----------------------
DEVINL void sdots_body(const float* __restrict__ x, const float* __restrict__ qs,
                       const float* __restrict__ qd, float* __restrict__ out_s,
                       float* __restrict__ out_d, int n, int b) {
    const int t = threadIdx.x, wv = t >> 6;
    const float* xr = x + (size_t)(b * 256 + n) * 768;
    float a0 = 0, a1 = 0, a2 = 0, a3 = 0;
#pragma unroll
    for (int i = 0; i < 3; i++) {
        int k = i * 256 + t;
        float xv = xr[k];
        a0 += xv * qs[k];
        a1 += xv * qs[768 + k];
        a2 += xv * qd[k];
        a3 += xv * qd[768 + k];
    }
    a0 = wredsum(a0); a1 = wredsum(a1); a2 = wredsum(a2); a3 = wredsum(a3);
    __shared__ float part[4][4];
    if ((t & 63) == 0) { part[wv][0] = a0; part[wv][1] = a1; part[wv][2] = a2; part[wv][3] = a3; }
    __syncthreads();
    if (t == 0) {
        float r0 = 0, r1 = 0, r2 = 0, r3 = 0;
#pragma unroll
        for (int i = 0; i < 4; i++) { r0 += part[i][0]; r1 += part[i][1]; r2 += part[i][2]; r3 += part[i][3]; }
        out_s[(b * 2 + 0) * 256 + n] = r0;
        out_s[(b * 2 + 1) * 256 + n] = r1;
        out_d[(b * 2 + 0) * 256 + n] = r2;
        out_d[(b * 2 + 1) * 256 + n] = r3;
    }
}

// ---------------- layer-1 attention (both heads per block) ------------------
DEVINL void att1_body(const float* __restrict__ e, const int* __restrict__ adj,
                      const float* __restrict__ s_s, const float* __restrict__ s_d,
                      const float* __restrict__ u1, us* __restrict__ attb,
                      int n, int bb) {
    __shared__ float eL[1792];
    __shared__ float smax[2][4], ssum[2][4];
    const int t = threadIdx.x, wv = t >> 6;
    const float* erow = e + (size_t)(bb * 256 + n) * 1792;
#pragma unroll
    for (int i = 0; i < 7; i++) eL[t + i * 256] = erow[t + i * 256];
    __syncthreads();
    float ss0 = s_s[(bb * 2 + 0) * 256 + n], ss1 = s_s[(bb * 2 + 1) * 256 + n];
    float sd0 = s_d[(bb * 2 + 0) * 256 + t], sd1 = s_d[(bb * 2 + 1) * 256 + t];
    float se0 = 0, se1 = 0;
#pragma unroll
    for (int k = 0; k < 7; k++) {
        float ev = eL[t * 7 + k];
        se0 += ev * u1[k];
        se1 += ev * u1[8 + k];
    }
    float sc0 = ss0 + sd0 + se0, sc1 = ss1 + sd1 + se1;
    sc0 = sc0 > 0.0f ? sc0 : 0.2f * sc0;
    sc1 = sc1 > 0.0f ? sc1 : 0.2f * sc1;
    bool ok = adj[(size_t)(bb * 256 + n) * 256 + t] > 0;
    sc0 = ok ? sc0 : -9e15f;
    sc1 = ok ? sc1 : -9e15f;
    float w0 = wredmax(sc0), w1 = wredmax(sc1);
    if ((t & 63) == 0) { smax[0][wv] = w0; smax[1][wv] = w1; }
    __syncthreads();
    float mx0 = fmaxf(fmaxf(smax[0][0], smax[0][1]), fmaxf(smax[0][2], smax[0][3]));
    float mx1 = fmaxf(fmaxf(smax[1][0], smax[1][1]), fmaxf(smax[1][2], smax[1][3]));
    float ex0 = __expf(sc0 - mx0), ex1 = __expf(sc1 - mx1);
    float su0 = wredsum(ex0), su1 = wredsum(ex1);
    if ((t & 63) == 0) { ssum[0][wv] = su0; ssum[1][wv] = su1; }
    __syncthreads();
    float i0 = 1.0f / (ssum[0][0] + ssum[0][1] + ssum[0][2] + ssum[0][3]);
    float i1 = 1.0f / (ssum[1][0] + ssum[1][1] + ssum[1][2] + ssum[1][3]);
    attb[((size_t)(bb * 2 + 0) * 256 + n) * 256 + t] = f2bf(ex0 * i0);
    attb[((size_t)(bb * 2 + 1) * 256 + n) * 256 + t] = f2bf(ex1 * i1);
}

// ---------------- Wh^T = (x @ W)^T via bf16 MFMA (64x64 tiles) --------------
DEVINL void gemm_xw_body(const us* __restrict__ A, const us* __restrict__ BT,
                         us* __restrict__ WhT, int mt, int ot, int h) {
    const int t = threadIdx.x, wv = t >> 6, l = t & 63;
    const int wm = wv >> 1, wn = wv & 1, lr = l & 15, lk = l >> 4;
    __shared__ us As[64][40];
    __shared__ us Bs[64][40];
    const int arow = t >> 2, acol = (t & 3) * 8;
    const us* Bh = BT + (size_t)h * 589824;
    f32x4 acc[2][2];
#pragma unroll
    for (int i = 0; i < 2; i++)
#pragma unroll
        for (int j = 0; j < 2; j++) acc[i][j] = (f32x4){0, 0, 0, 0};
    for (int k0 = 0; k0 < 768; k0 += 32) {
        __syncthreads();
        *(bf16x8*)&As[arow][acol] = *(const bf16x8*)&A[(size_t)(mt * 64 + arow) * 768 + k0 + acol];
        *(bf16x8*)&Bs[arow][acol] = *(const bf16x8*)&Bh[(size_t)(ot * 64 + arow) * 768 + k0 + acol];
        __syncthreads();
        bf16x8 af[2], bfv[2];
#pragma unroll
        for (int i = 0; i < 2; i++) af[i] = *(const bf16x8*)&As[wm * 32 + i * 16 + lr][lk * 8];
#pragma unroll
        for (int j = 0; j < 2; j++) bfv[j] = *(const bf16x8*)&Bs[wn * 32 + j * 16 + lr][lk * 8];
#pragma unroll
        for (int i = 0; i < 2; i++)
#pragma unroll
            for (int j = 0; j < 2; j++)
                acc[i][j] = __builtin_amdgcn_mfma_f32_16x16x32_bf16(af[i], bfv[j], acc[i][j], 0, 0, 0);
    }
#pragma unroll
    for (int i = 0; i < 2; i++)
#pragma unroll
        for (int j = 0; j < 2; j++) {
            int n0 = mt * 64 + wm * 32 + i * 16 + lk * 4;
            int og = ot * 64 + wn * 32 + j * 16 + lr;
            int b = n0 >> 8, n = n0 & 255;
            us pk[4];
#pragma unroll
            for (int r = 0; r < 4; r++) pk[r] = f2bf(acc[i][j][r]);
            *(bf16x4*)&WhT[((size_t)(b * 2 + h) * 768 + og) * 256 + n] = *(bf16x4*)pk;
        }
}

// ------- x' = 0.5*(elu(att@Wh)_h0+elu_h1)+resid (32x64 tiles) ---------------
DEVINL void gemm_att_body(const us* __restrict__ attb, const us* __restrict__ WhT,
                          const float* __restrict__ resid, float* __restrict__ xout,
                          us* __restrict__ xbout, int mt, int ot, int b) {
    const int t = threadIdx.x, wv = t >> 6, l = t & 63;
    const int wm = wv >> 1, wn = wv & 1, lr = l & 15, lk = l >> 4;
    __shared__ us As2[32][40];
    __shared__ us Bs2[64][40];
    float res[2][4] = {};
    for (int h = 0; h < 2; h++) {
        const us* Ah = attb + (size_t)(b * 2 + h) * 65536;
        const us* Bh = WhT + (size_t)(b * 2 + h) * 196608;
        f32x4 acc[2];
        acc[0] = (f32x4){0, 0, 0, 0};
        acc[1] = (f32x4){0, 0, 0, 0};
        for (int k0 = 0; k0 < 256; k0 += 32) {
            __syncthreads();
            if (t < 128) {
                int ar = t >> 2, ac = (t & 3) * 8;
                *(bf16x8*)&As2[ar][ac] = *(const bf16x8*)&Ah[(size_t)(mt * 32 + ar) * 256 + k0 + ac];
            }
            {
                int br = t >> 2, bc = (t & 3) * 8;
                *(bf16x8*)&Bs2[br][bc] = *(const bf16x8*)&Bh[(size_t)(ot * 64 + br) * 256 + k0 + bc];
            }
            __syncthreads();
            bf16x8 af = *(const bf16x8*)&As2[wm * 16 + lr][lk * 8];
#pragma unroll
            for (int j = 0; j < 2; j++) {
                bf16x8 bv = *(const bf16x8*)&Bs2[wn * 32 + j * 16 + lr][lk * 8];
                acc[j] = __builtin_amdgcn_mfma_f32_16x16x32_bf16(af, bv, acc[j], 0, 0, 0);
            }
        }
#pragma unroll
        for (int j = 0; j < 2; j++)
#pragma unroll
            for (int r = 0; r < 4; r++) {
                float v = acc[j][r];
                res[j][r] += (v > 0.0f ? v : (expf(v) - 1.0f)); // elu
            }
        __syncthreads();
    }
#pragma unroll
    for (int j = 0; j < 2; j++) {
        int n0 = mt * 32 + wm * 16 + lk * 4;
        int og = ot * 64 + wn * 32 + j * 16 + lr;
#pragma unroll
        for (int r = 0; r < 4; r++) {
            size_t idx = (size_t)(b * 256 + n0 + r) * 768 + og;
            float v = 0.5f * res[j][r] + resid[idx];
            if (xout) xout[idx] = v;
            if (xbout) xbout[idx] = f2bf(v);
        }
    }
}

// ---------------- stage-6 shared-memory union (max, not sum) ----------------
union Smem6 {
    struct {
        us    blB[1536 * 8];       // 24576 B
        float eL[1792];            // 7168 B
        float aL1[2][256];         // 2048 B
        float aL2[2][256];         // 2048 B
        float smax[2][4];          // 32 B
        float ssum[2][4];          // 32 B
    } a;                           // 35904 B
    struct {
        us aA[2][32][264];         // 33792 B
        us Bs2[64][40];            // 5120 B
    } b;                           // 38912 B  -> 4 blocks/CU
};

// ---------------- fused att2 + e2 row stream --------------------------------
DEVINL void att2e2_body(const float* __restrict__ e, const int* __restrict__ adj,
                        const float* __restrict__ s_s, const float* __restrict__ s_d,
                        const float* __restrict__ w, const us* __restrict__ att1b,
                        const us* __restrict__ Bfrag, float* __restrict__ e2out,
                        Smem6& sm, int bb, int n) {
    const int t = threadIdx.x, wv4 = t >> 6;
    for (int i = t; i < 1536; i += 256)
        *(bf16x8*)&sm.a.blB[i * 8] = *(const bf16x8*)&Bfrag[(size_t)i * 8];
    const float* erow = e + (size_t)(bb * 256 + n) * 1792;
#pragma unroll
    for (int i = 0; i < 7; i++) sm.a.eL[t + i * 256] = erow[t + i * 256];
    const size_t a1base = (size_t)bb * 131072 + n * 256;
    float a10 = bf2f(att1b[a1base + t]);
    float a11 = bf2f(att1b[a1base + 65536 + t]);
    sm.a.aL1[0][t] = a10;
    sm.a.aL1[1][t] = a11;
    __syncthreads();
    float ss0 = s_s[(bb * 2 + 0) * 256 + n], ss1 = s_s[(bb * 2 + 1) * 256 + n];
    float sd0 = s_d[(bb * 2 + 0) * 256 + t], sd1 = s_d[(bb * 2 + 1) * 256 + t];
    float ew00 = 0, ew01 = 0, ew10 = 0, ew11 = 0;
#pragma unroll
    for (int k = 0; k < 7; k++) {
        float ev = sm.a.eL[t * 7 + k];
        ew00 += ev * w[k];
        ew01 += ev * w[8 + k];
        ew10 += ev * w[16 + k];
        ew11 += ev * w[24 + k];
    }
    float sc0 = ss0 + sd0 + a10 * ew00 + a11 * ew10;
    float sc1 = ss1 + sd1 + a10 * ew01 + a11 * ew11;
    sc0 = sc0 > 0.0f ? sc0 : 0.2f * sc0;
    sc1 = sc1 > 0.0f ? sc1 : 0.2f * sc1;
    bool ok = adj[(size_t)(bb * 256 + n) * 256 + t] > 0;
    sc0 = ok ? sc0 : -9e15f;
    sc1 = ok ? sc1 : -9e15f;
    float w0 = wredmax(sc0), w1 = wredmax(sc1);
    if ((t & 63) == 0) { sm.a.smax[0][wv4] = w0; sm.a.smax[1][wv4] = w1; }
    __syncthreads();
    float mx0 = fmaxf(fmaxf(sm.a.smax[0][0], sm.a.smax[0][1]), fmaxf(sm.a.smax[0][2], sm.a.smax[0][3]));
    float mx1 = fmaxf(fmaxf(sm.a.smax[1][0], sm.a.smax[1][1]), fmaxf(sm.a.smax[1][2], sm.a.smax[1][3]));
    float ex0 = __expf(sc0 - mx0), ex1 = __expf(sc1 - mx1);
    float su0 = wredsum(ex0), su1 = wredsum(ex1);
    if ((t & 63) == 0) { sm.a.ssum[0][wv4] = su0; sm.a.ssum[1][wv4] = su1; }
    __syncthreads();
    float i0 = 1.0f / (sm.a.ssum[0][0] + sm.a.ssum[0][1] + sm.a.ssum[0][2] + sm.a.ssum[0][3]);
    float i1 = 1.0f / (sm.a.ssum[1][0] + sm.a.ssum[1][1] + sm.a.ssum[1][2] + sm.a.ssum[1][3]);
    sm.a.aL2[0][t] = ex0 * i0;
    sm.a.aL2[1][t] = ex1 * i1;
    __syncthreads();
    // e2 stream
    const int wv = t >> 6, l = t & 63, le = l & 15, lq = l >> 4;
    const int h1 = lq >> 1, h2 = lq & 1;
    bf16x8 av[4];
#pragma unroll
    for (int g = 0; g < 4; g++) {
        int m = g * 64 + wv * 16 + le;
        float c = sm.a.aL1[h1][m] * sm.a.aL2[h2][m];
        us pk[8];
#pragma unroll
        for (int j = 0; j < 7; j++) pk[j] = f2bf(c * sm.a.eL[m * 7 + j]);
        pk[7] = 0;
        av[g] = *(bf16x8*)pk;
    }
    const f32x4 zero = {0, 0, 0, 0};
    const size_t rowbase = (size_t)bb * 65536 + n * 256;
#pragma unroll
    for (int cg = 0; cg < 3; cg++) {
        bf16x8 bfr[8];
#pragma unroll
        for (int i = 0; i < 8; i++) bfr[i] = *(const bf16x8*)&sm.a.blB[(cg * 512 + i * 64 + l) * 8];
        for (int g = 0; g < 4; g++) {
            size_t eidx = rowbase + g * 64 + wv * 16 + le;
#pragma unroll
            for (int i = 0; i < 8; i++) {
                f32x4 acc = __builtin_amdgcn_mfma_f32_16x16x32_bf16(bfr[i], av[g], zero, 0, 0, 0);
                *(f32x4*)&e2out[eidx * 384 + cg * 128 + i * 16 + lq * 4] = acc;
            }
        }
    }
}

// ---- fat x2 GEMM (192 blocks): recompute att2 for 32 rows, 32x64 tile ------
DEVINL void gemm_att2_fat(const float* __restrict__ e, const int* __restrict__ adj,
                          const float* __restrict__ s2s, const float* __restrict__ s2d,
                          const float* __restrict__ wbuf, const us* __restrict__ att1b,
                          const us* __restrict__ WhT2, const float* __restrict__ resid,
                          float* __restrict__ x2out, Smem6& sm, int mt, int ot, int b) {
    const int t = threadIdx.x, wv = t >> 6, l = t & 63;
    // ---- phase A (R10-proven): wave wv computes att2 for rows wv*8..wv*8+7
    for (int rr = 0; rr < 8; rr++) {
        const int r = wv * 8 + rr, n = mt * 32 + r, m0 = l * 4;
        const float* ep = e + ((size_t)(b * 256 + n) * 256 + m0) * 7;
        float ev[4][7];
#pragma unroll
        for (int mm = 0; mm < 4; mm++)
#pragma unroll
            for (int k = 0; k < 7; k++) ev[mm][k] = ep[mm * 7 + k];
        const int* adjp = adj + (size_t)(b * 256 + n) * 256 + m0;
        float ss0 = s2s[(b * 2 + 0) * 256 + n], ss1 = s2s[(b * 2 + 1) * 256 + n];
        float sc0[4], sc1[4];
#pragma unroll
        for (int mm = 0; mm < 4; mm++) {
            int m = m0 + mm;
            float sd0 = s2d[(b * 2 + 0) * 256 + m];
            float sd1 = s2d[(b * 2 + 1) * 256 + m];
            float a10 = bf2f(att1b[((size_t)(b * 2 + 0) * 256 + n) * 256 + m]);
            float a11 = bf2f(att1b[((size_t)(b * 2 + 1) * 256 + n) * 256 + m]);
            float ew00 = 0, ew01 = 0, ew10 = 0, ew11 = 0;
#pragma unroll
            for (int k = 0; k < 7; k++) {
                float evk = ev[mm][k];
                ew00 += evk * wbuf[k];
                ew01 += evk * wbuf[8 + k];
                ew10 += evk * wbuf[16 + k];
                ew11 += evk * wbuf[24 + k];
            }
            float s0 = ss0 + sd0 + a10 * ew00 + a11 * ew10;
            float s1 = ss1 + sd1 + a10 * ew01 + a11 * ew11;
            s0 = s0 > 0.0f ? s0 : 0.2f * s0;
            s1 = s1 > 0.0f ? s1 : 0.2f * s1;
            bool ok = adjp[mm] > 0;
            sc0[mm] = ok ? s0 : -9e15f;
            sc1[mm] = ok ? s1 : -9e15f;
        }
        float mx0 = fmaxf(fmaxf(sc0[0], sc0[1]), fmaxf(sc0[2], sc0[3]));
        float mx1 = fmaxf(fmaxf(sc1[0], sc1[1]), fmaxf(sc1[2], sc1[3]));
        mx0 = wredmax(mx0); mx1 = wredmax(mx1);
        float ex0[4], ex1[4], su0 = 0, su1 = 0;
#pragma unroll
        for (int mm = 0; mm < 4; mm++) {
            ex0[mm] = __expf(sc0[mm] - mx0); su0 += ex0[mm];
            ex1[mm] = __expf(sc1[mm] - mx1); su1 += ex1[mm];
        }
        su0 = wredsum(su0); su1 = wredsum(su1);
        float i0 = 1.0f / su0, i1 = 1.0f / su1;
        us p0[4], p1[4];
#pragma unroll
        for (int mm = 0; mm < 4; mm++) { p0[mm] = f2bf(ex0[mm] * i0); p1[mm] = f2bf(ex1[mm] * i1); }
        *(bf16x4*)&sm.b.aA[0][r][m0] = *(bf16x4*)p0;
        *(bf16x4*)&sm.b.aA[1][r][m0] = *(bf16x4*)p1;
    }
    __syncthreads();
    // ---- phase B: 32x64 GEMM, A from LDS aA, B staged via LDS (R4 pattern)
    const int wm = wv >> 1, wn = wv & 1, lr = l & 15, lk = l >> 4;
    float res[2][4] = {};
    for (int h = 0; h < 2; h++) {
        const us* Bh = WhT2 + (size_t)(b * 2 + h) * 196608;
        f32x4 acc[2];
        acc[0] = (f32x4){0, 0, 0, 0};
        acc[1] = (f32x4){0, 0, 0, 0};
        for (int k0 = 0; k0 < 256; k0 += 32) {
            __syncthreads();
            {
                int br = t >> 2, bc = (t & 3) * 8;
                *(bf16x8*)&sm.b.Bs2[br][bc] = *(const bf16x8*)&Bh[(size_t)(ot * 64 + br) * 256 + k0 + bc];
            }
            __syncthreads();
            bf16x8 af = *(const bf16x8*)&sm.b.aA[h][wm * 16 + lr][k0 + lk * 8];
#pragma unroll
            for (int j = 0; j < 2; j++) {
                bf16x8 bv = *(const bf16x8*)&sm.b.Bs2[wn * 32 + j * 16 + lr][lk * 8];
                acc[j] = __builtin_amdgcn_mfma_f32_16x16x32_bf16(af, bv, acc[j], 0, 0, 0);
            }
        }
#pragma unroll
        for (int j = 0; j < 2; j++)
#pragma unroll
            for (int r = 0; r < 4; r++) {
                float v = acc[j][r];
                res[j][r] += (v > 0.0f ? v : (expf(v) - 1.0f)); // elu
            }
        __syncthreads();
    }
#pragma unroll
    for (int j = 0; j < 2; j++) {
        int n0 = mt * 32 + wm * 16 + lk * 4;
        int og = ot * 64 + wn * 32 + j * 16 + lr;
#pragma unroll
        for (int r = 0; r < 4; r++) {
            size_t idx = (size_t)(b * 256 + n0 + r) * 768 + og;
            x2out[idx] = 0.5f * res[j][r] + resid[idx];
        }
    }
}

// ========================= stage kernels ====================================
__global__ __launch_bounds__(256) void stage1(
    const float* W1, const float* W2, const float* We1, const float* We2,
    const float* a1s, const float* a1d, const float* a1e,
    const float* a2s, const float* a2d, const float* x,
    us* W1T, us* W2T, us* xb, float* q, float* u1, float* Mcat) {
    int b = blockIdx.x;
    if (b < 6)          mcat_body(We1, We2, Mcat, b & 1, b >> 1);
    else if (b < 199)   pre_qu_body(W1, W2, We1, a1s, a1d, a1e, a2s, a2d, q, u1, b - 6);
    else if (b < 487)   transpose_body(W1, W1T, b - 199);
    else if (b < 775)   transpose_body(W2, W2T, b - 487);
    else                cvt_body(x, xb, b - 775);
}

__global__ __launch_bounds__(256) void stage2(
    const float* Mcat, const float* a2e, float* wbuf, us* Bfrag,
    const float* x, const float* qs, const float* qd, float* s1s, float* s1d) {
    int b = blockIdx.x;
    if (b < 1)        wcalc_body(Mcat, a2e, wbuf);
    else if (b < 25)  bfrag_body(Mcat, Bfrag, b - 1);
    else { int i = b - 25; sdots_body(x, qs, qd, s1s, s1d, i & 255, i >> 8); }
}

__global__ __launch_bounds__(256) void stage3(
    const float* e, const int* adj, const float* s1s, const float* s1d,
    const float* u1, us* att1b, const us* xb, const us* W1T, us* WhT1) {
    int b = blockIdx.x;
    if (b < 512) att1_body(e, adj, s1s, s1d, u1, att1b, b & 255, b >> 8);
    else { int g = b - 512; gemm_xw_body(xb, W1T, WhT1, g & 7, (g >> 3) % 12, g / 96); }
}

__global__ __launch_bounds__(256) void stage4(
    const us* att1b, const us* WhT1, const float* x, float* x1, us* xb1) {
    int b = blockIdx.x;
    gemm_att_body(att1b, WhT1, x, x1, xb1, b & 7, (b >> 3) % 12, b / 96);
}

__global__ __launch_bounds__(256) void stage5(
    const float* x1, const float* qs, const float* qd, float* s2s, float* s2d,
    const us* xb1, const us* W2T, us* WhT2) {
    int b = blockIdx.x;
    if (b < 512) sdots_body(x1, qs, qd, s2s, s2d, b & 255, b >> 8);
    else { int g = b - 512; gemm_xw_body(xb1, W2T, WhT2, g & 7, (g >> 3) % 12, g / 96); }
}

__global__ __launch_bounds__(256) void stage6(
    const float* e, const int* adj, const float* s2s, const float* s2d,
    const float* wbuf, const us* att1b, const us* Bfrag, float* e2out,
    const us* WhT2, const float* x, float* x2out) {
    __shared__ Smem6 sm;   // union: 38.9 KB -> 4 blocks/CU
    int b = blockIdx.x;
    if (b < 192) {
        int bb = b & 1, mt = (b >> 1) & 7, ot = b >> 4;
        gemm_att2_fat(e, adj, s2s, s2d, wbuf, att1b, WhT2, x, x2out, sm, mt, ot, bb);
    } else {
        int r = b - 192;
        att2e2_body(e, adj, s2s, s2d, wbuf, att1b, Bfrag, e2out, sm, r >> 8, r & 255);
    }
}

// ---------------------------------------------------------------------------
extern "C" void kernel_launch(void* const* d_in, const int* in_sizes, int n_in,
                              void* d_out, int out_size, void* d_ws, size_t ws_size,
                              hipStream_t stream) {
    const float* x   = (const float*)d_in[0];
    const int*   adj = (const int*)d_in[1];
    const float* e   = (const float*)d_in[2];
    const float* W1  = (const float*)d_in[3];
    const float* We1 = (const float*)d_in[4];
    const float* a1s = (const float*)d_in[5];
    const float* a1d = (const float*)d_in[6];
    const float* a1e = (const float*)d_in[7];
    const float* W2  = (const float*)d_in[8];
    const float* We2 = (const float*)d_in[9];
    const float* a2s = (const float*)d_in[10];
    const float* a2d = (const float*)d_in[11];
    const float* a2e = (const float*)d_in[12];

    float* out   = (float*)d_out;
    float* x2out = out;                  // [2][256][768]
    float* e2out = out + 393216;         // [2][256][256][384]

    char* ws = (char*)d_ws;
    float* q     = (float*)(ws + 0);         // [4][2][768]
    float* u1    = (float*)(ws + 24576);     // [2][8]
    float* wbuf  = (float*)(ws + 24640);     // [2][2][8]
    float* Mcat  = (float*)(ws + 24832);     // [32][384]
    us*    Bfrag = (us*)(ws + 73984);        // [24][64][8]
    float* s1s   = (float*)(ws + 98560);
    float* s1d   = (float*)(ws + 102656);
    float* s2s   = (float*)(ws + 106752);
    float* s2d   = (float*)(ws + 110848);
    us*    att1b = (us*)(ws + 114944);       // [2][2][256][256] bf16
    us*    W1T   = (us*)(ws + 1163520);      // [2][768][768] bf16
    us*    W2T   = (us*)(ws + 3522816);
    us*    xb    = (us*)(ws + 5882112);      // [512][768] bf16
    us*    xb1   = (us*)(ws + 6668544);
    us*    WhT1  = (us*)(ws + 7454976);      // [2][2][768][256] bf16
    us*    WhT2  = (us*)(ws + 9027840);
    float* x1    = (float*)(ws + 10600704);  // [512][768] f32

    stage1<<<967, 256, 0, stream>>>(W1, W2, We1, We2, a1s, a1d, a1e, a2s, a2d,
                                    x, W1T, W2T, xb, q, u1, Mcat);
    stage2<<<537, 256, 0, stream>>>(Mcat, a2e, wbuf, Bfrag, x, q + 0, q + 1536, s1s, s1d);
    stage3<<<704, 256, 0, stream>>>(e, adj, s1s, s1d, u1, att1b, xb, W1T, WhT1);
    stage4<<<192, 256, 0, stream>>>(att1b, WhT1, x, x1, xb1);
    stage5<<<704, 256, 0, stream>>>(x1, q + 3072, q + 4608, s2s, s2d, xb1, W2T, WhT2);
    stage6<<<704, 256, 0, stream>>>(e, adj, s2s, s2d, wbuf, att1b, Bfrag, e2out,
                                    WhT2, x, x2out);
}